// Round 3
// baseline (85.693 us; speedup 1.0000x reference)
//
#include <hip/hip_runtime.h>

typedef __attribute__((ext_vector_type(8)))  __bf16 bf16x8;
typedef __attribute__((ext_vector_type(4)))  __bf16 bf16x4;
typedef __attribute__((ext_vector_type(16))) float  f32x16;
typedef __attribute__((ext_vector_type(4)))  float  f32x4;

#define B_    16
#define N_    2048
#define D_    64
#define QBLK  64             // q rows per block (2 q-waves x 32)
#define KVBLK 32
#define NT    (N_ / KVBLK)   // 64 tiles
#define NG    4              // KV groups per block
#define TPG   (NT / NG)      // 16 tiles per group

static __device__ __forceinline__ float fast_exp2(float x) {
#if __has_builtin(__builtin_amdgcn_exp2f)
    return __builtin_amdgcn_exp2f(x);
#else
    return __expf(x * 0.6931471805599453f);
#endif
}

__global__ __launch_bounds__(512, 4)
void attn_fwd(const float* __restrict__ Qp, const float* __restrict__ Kp,
              const float* __restrict__ Vp, float* __restrict__ Op)
{
    __shared__ uint4 smem_u4[4096];            // 64 KiB
    char* smem = (char*)smem_u4;

    const int tid  = threadIdx.x;
    const int wv   = tid >> 6;                 // wave 0..7
    const int g    = wv >> 1;                  // KV group 0..3
    const int w    = wv & 1;                   // q-wave within group
    const int lane = tid & 63;
    const int h    = lane >> 5;
    const int qcol = lane & 31;
    const int tg   = tid & 127;                // thread within group

    const int bx    = blockIdx.x;
    const int xcd   = bx & 7, local = bx >> 3;
    const int batch = (xcd << 1) | (local & 1);   // 2 batches per XCD -> L2-local K/V
    const int qtile = local >> 1;                  // 0..31
    const int q0w   = qtile * QBLK + w * 32;

    const float SL2E = 0.18033688011112042f;   // (1/sqrt(64)) * log2(e)
    const size_t bboff = (size_t)batch * (N_ * D_);

    char* gbase = smem + g * 16384;            // group staging: 2 bufs x (K 4K + Vt 4K)

    // ---------------- Q fragments (registers, reused across all tiles) ------
    const float* qrow = Qp + bboff + (size_t)(q0w + qcol) * D_ + h * 8;
    bf16x8 qf[4];
#pragma unroll
    for (int m = 0; m < 4; ++m) {
        f32x4 a = *reinterpret_cast<const f32x4*>(qrow + m * 16);
        f32x4 b = *reinterpret_cast<const f32x4*>(qrow + m * 16 + 4);
#pragma unroll
        for (int j = 0; j < 4; ++j) { qf[m][j] = (__bf16)a[j]; qf[m][4 + j] = (__bf16)b[j]; }
    }

    // ---------------- staging (global -> reg -> LDS), 128 thr per group -----
    const int krow = tg >> 2,  kcol = (tg & 3) * 16;   // K: 32 rows, 4 thr/row
    const int vrow = tg & 31,  vcol = (tg >> 5) * 16;  // V: 32 kv rows, 16 d each
    const float* ksrc0 = Kp + bboff + (size_t)krow * D_ + kcol;
    const float* vsrc0 = Vp + bboff + (size_t)vrow * D_ + vcol;

    f32x4 kr[4], vr[4];
    auto load_tile = [&](int t) {              // t = global tile index
        const float* ks = ksrc0 + (size_t)t * KVBLK * D_;
        const float* vs = vsrc0 + (size_t)t * KVBLK * D_;
#pragma unroll
        for (int i = 0; i < 4; ++i) kr[i] = *reinterpret_cast<const f32x4*>(ks + 4 * i);
#pragma unroll
        for (int i = 0; i < 4; ++i) vr[i] = *reinterpret_cast<const f32x4*>(vs + 4 * i);
    };

    auto write_tile = [&](int b) {
        char* kb = gbase + b * 8192;
        char* vb = gbase + b * 8192 + 4096;
        // K: row-major [32][64] bf16 (128B rows), XOR-swizzled (row&7)<<4
        const int xr = (krow & 7) << 4;
        bf16x8 w0, w1;
#pragma unroll
        for (int j = 0; j < 4; ++j) {
            w0[j] = (__bf16)kr[0][j];  w0[4 + j] = (__bf16)kr[1][j];
            w1[j] = (__bf16)kr[2][j];  w1[4 + j] = (__bf16)kr[3][j];
        }
        *reinterpret_cast<bf16x8*>(kb + krow * 128 + ((kcol * 2)      ^ xr)) = w0;
        *reinterpret_cast<bf16x8*>(kb + krow * 128 + ((kcol * 2 + 16) ^ xr)) = w1;
        // Vt: [64 d][32 kv] bf16 (64B rows), XOR-swizzled (d&7)<<3
#pragma unroll 16
        for (int i = 0; i < 16; ++i) {
            const int d = vcol + i;
            *reinterpret_cast<__bf16*>(vb + d * 64 + ((vrow * 2) ^ ((d & 7) << 3))) =
                (__bf16)vr[i >> 2][i & 3];
        }
    };

    // ---------------- accumulators / softmax state --------------------------
    f32x16 o0, o1;
#pragma unroll
    for (int i = 0; i < 16; ++i) { o0[i] = 0.f; o1[i] = 0.f; }
    float m_run = -1e30f, l_run = 0.f;

    const int kx = (qcol & 7) << 4;            // K-read swizzle for this lane's row

    load_tile(g);
    write_tile(0);
    __syncthreads();

    for (int it = 0; it < TPG; ++it) {
        const int cur = it & 1;
        if (it + 1 < TPG) load_tile(NG * (it + 1) + g);   // issue next loads early

        const char* kb = gbase + cur * 8192;
        const char* vb = gbase + cur * 8192 + 4096;

        // ---- QK^T : S^T[kv][q] = mfma(A=K, B=Q^T), kv = 0..31 ----
        f32x16 s;
#pragma unroll
        for (int i = 0; i < 16; ++i) s[i] = 0.f;
        __builtin_amdgcn_s_setprio(1);
#pragma unroll
        for (int m = 0; m < 4; ++m) {
            const int col = m * 32 + h * 16;
            bf16x8 k0 = *reinterpret_cast<const bf16x8*>(kb + qcol * 128 + (col ^ kx));
            s = __builtin_amdgcn_mfma_f32_32x32x16_bf16(k0, qf[m], s, 0, 0, 0);
        }
        __builtin_amdgcn_s_setprio(0);

        // ---- online softmax (tree max, depth 4) ----
        float t8[8];
#pragma unroll
        for (int i = 0; i < 8; ++i) t8[i] = fmaxf(s[i], s[8 + i]);
        float t4a = fmaxf(t8[0], t8[1]), t4b = fmaxf(t8[2], t8[3]);
        float t4c = fmaxf(t8[4], t8[5]), t4d = fmaxf(t8[6], t8[7]);
        float tmax = fmaxf(fmaxf(t4a, t4b), fmaxf(t4c, t4d));
        tmax = fmaxf(tmax, __shfl_xor(tmax, 32));

        if (!__all(tmax <= m_run + 16.0f)) {   // defer-max, THR=16 raw => p <= 7.4
            const float mnew  = fmaxf(m_run, tmax);
            const float alpha = fast_exp2((m_run - mnew) * SL2E);
            l_run *= alpha;
#pragma unroll
            for (int i = 0; i < 16; ++i) { o0[i] *= alpha; o1[i] *= alpha; }
            m_run = mnew;
        }

        const float nmk = -m_run * SL2E;
        float ps0 = 0.f, ps1 = 0.f, ps2 = 0.f, ps3 = 0.f;
        bf16x8 pfa, pfb;
#pragma unroll
        for (int i = 0; i < 4; ++i) {
            float p0 = fast_exp2(fmaf(s[i],      SL2E, nmk));
            float p1 = fast_exp2(fmaf(s[4 + i],  SL2E, nmk));
            float p2 = fast_exp2(fmaf(s[8 + i],  SL2E, nmk));
            float p3 = fast_exp2(fmaf(s[12 + i], SL2E, nmk));
            ps0 += p0; ps1 += p1; ps2 += p2; ps3 += p3;
            pfa[i] = (__bf16)p0; pfa[4 + i] = (__bf16)p1;
            pfb[i] = (__bf16)p2; pfb[4 + i] = (__bf16)p3;
        }
        l_run += (ps0 + ps1) + (ps2 + ps3);

        // ---- PV : O^T[d][q] += mfma(A=Vt, B=P) ----
        __builtin_amdgcn_s_setprio(1);
#pragma unroll
        for (int db = 0; db < 2; ++db) {
            const int drow = db * 32 + qcol;
            const char* vrowp = vb + drow * 64;
            const int vxx = (drow & 7) << 3;
            f32x16& oo = db ? o1 : o0;
#pragma unroll
            for (int sub = 0; sub < 2; ++sub) {
                const int cb = sub * 32 + h * 8;
                bf16x4 v0 = *reinterpret_cast<const bf16x4*>(vrowp + ((cb)      ^ vxx));
                bf16x4 v1 = *reinterpret_cast<const bf16x4*>(vrowp + ((cb + 16) ^ vxx));
                bf16x8 vf;
#pragma unroll
                for (int j = 0; j < 4; ++j) { vf[j] = v0[j]; vf[4 + j] = v1[j]; }
                oo = __builtin_amdgcn_mfma_f32_32x32x16_bf16(vf, sub ? pfb : pfa, oo, 0, 0, 0);
            }
        }
        __builtin_amdgcn_s_setprio(0);

        if (it + 1 < TPG) write_tile((it + 1) & 1);
        __syncthreads();
    }

    // ---------------- 4-way cross-group combine through LDS -----------------
    const float lt = l_run + __shfl_xor(l_run, 32);
    float* slabF = (float*)smem;               // groups 1..3: 3 x 4096 floats (48 KB)
    float* mlF   = slabF + 12288;              // 512 floats (2 KB)
    const int slot = w * 64 + lane;            // 0..127

    if (g > 0) {
        float* dst = slabF + (g - 1) * 4096 + slot * 32;
#pragma unroll
        for (int i = 0; i < 16; ++i) { dst[i] = o0[i]; dst[16 + i] = o1[i]; }
    }
    if (h == 0) {
        mlF[((g * 2 + w) * 32 + qcol) * 2]     = m_run;
        mlF[((g * 2 + w) * 32 + qcol) * 2 + 1] = lt;
    }
    __syncthreads();

    if (g == 0) {
        float m_all[4], l_all[4];
        m_all[0] = m_run; l_all[0] = lt;
#pragma unroll
        for (int gg = 1; gg < 4; ++gg) {
            m_all[gg] = mlF[((gg * 2 + w) * 32 + qcol) * 2];
            l_all[gg] = mlF[((gg * 2 + w) * 32 + qcol) * 2 + 1];
        }
        const float mm = fmaxf(fmaxf(m_all[0], m_all[1]), fmaxf(m_all[2], m_all[3]));
        const float a0 = fast_exp2((m_all[0] - mm) * SL2E);
        float L = a0 * l_all[0];
#pragma unroll
        for (int i = 0; i < 16; ++i) { o0[i] *= a0; o1[i] *= a0; }
#pragma unroll
        for (int gg = 1; gg < 4; ++gg) {
            const float ag = fast_exp2((m_all[gg] - mm) * SL2E);
            L += ag * l_all[gg];
            const float* src = slabF + (gg - 1) * 4096 + slot * 32;
#pragma unroll
            for (int i = 0; i < 16; ++i) {
                o0[i] = fmaf(ag, src[i],      o0[i]);
                o1[i] = fmaf(ag, src[16 + i], o1[i]);
            }
        }
        const float inv = 1.0f / L;
        float* orow = Op + bboff + (size_t)(q0w + qcol) * D_;
#pragma unroll
        for (int gg8 = 0; gg8 < 4; ++gg8) {
            f32x4 v, v2;
#pragma unroll
            for (int r = 0; r < 4; ++r) {
                v[r]  = o0[4 * gg8 + r] * inv;
                v2[r] = o1[4 * gg8 + r] * inv;
            }
            *reinterpret_cast<f32x4*>(orow + gg8 * 8 + 4 * h)      = v;
            *reinterpret_cast<f32x4*>(orow + 32 + gg8 * 8 + 4 * h) = v2;
        }
    }
}

extern "C" void kernel_launch(void* const* d_in, const int* in_sizes, int n_in,
                              void* d_out, int out_size, void* d_ws, size_t ws_size,
                              hipStream_t stream) {
    const float* Q = (const float*)d_in[0];
    const float* K = (const float*)d_in[1];
    const float* V = (const float*)d_in[2];
    float* O = (float*)d_out;
    dim3 grid(512), block(512);
    hipLaunchKernelGGL(attn_fwd, grid, block, 0, stream, Q, K, V, O);
}

// Round 4
// 41.609 us; speedup vs baseline: 2.0595x; 2.0595x over previous
//
#include <hip/hip_runtime.h>

typedef __attribute__((ext_vector_type(8)))  __bf16 bf16x8;
typedef __attribute__((ext_vector_type(4)))  __bf16 bf16x4;
typedef __attribute__((ext_vector_type(16))) float  f32x16;
typedef __attribute__((ext_vector_type(4)))  float  f32x4;

#define B_    16
#define N_    2048
#define D_    64
#define QBLK  128            // q rows per block (4 q-waves x 32, shared by all groups)
#define KVBLK 32
#define NT    (N_ / KVBLK)   // 64 tiles
#define NG    4              // KV groups per block (16 waves total)
#define TPG   (NT / NG)      // 16 tiles per group

static __device__ __forceinline__ float fast_exp2(float x) {
#if __has_builtin(__builtin_amdgcn_exp2f)
    return __builtin_amdgcn_exp2f(x);
#else
    return __expf(x * 0.6931471805599453f);
#endif
}

__global__ __launch_bounds__(1024, 4)
void attn_fwd(const float* __restrict__ Qp, const float* __restrict__ Kp,
              const float* __restrict__ Vp, float* __restrict__ Op)
{
    __shared__ uint4 smem_u4[4096];            // 64 KiB: 4 groups x 2 slots x (K 4K + Vt 4K)
    char* smem = (char*)smem_u4;

    const int tid  = threadIdx.x;
    const int g    = tid >> 8;                 // KV group 0..3
    const int tg   = tid & 255;                // thread within group
    const int lane = tid & 63;
    const int w    = (tid >> 6) & 3;           // q-wave 0..3 within group
    const int h    = lane >> 5;
    const int qcol = lane & 31;

    const int bx    = blockIdx.x;              // grid 256 = 1 block/CU
    const int batch = ((bx & 7) << 1) | ((bx >> 3) & 1);   // 2 batches per XCD
    const int qtile = bx >> 4;                 // 0..15
    const int q0w   = qtile * QBLK + w * 32;

    const float SL2E = 0.18033688011112042f;   // (1/sqrt(64)) * log2(e)
    const size_t bboff = (size_t)batch * (N_ * D_);

    char* gbase = smem + g * 16384;            // group staging: 2 slots x 8 KiB

    // ---------------- Q fragments (registers, reused across all tiles) ------
    const float* qrow = Qp + bboff + (size_t)(q0w + qcol) * D_ + h * 8;
    bf16x8 qf[4];
#pragma unroll
    for (int m = 0; m < 4; ++m) {
        f32x4 a = *reinterpret_cast<const f32x4*>(qrow + m * 16);
        f32x4 b = *reinterpret_cast<const f32x4*>(qrow + m * 16 + 4);
#pragma unroll
        for (int j = 0; j < 4; ++j) { qf[m][j] = (__bf16)a[j]; qf[m][4 + j] = (__bf16)b[j]; }
    }

    // ---------------- staging (global -> reg -> LDS), 256 thr per group -----
    // K tile 32x64 fp32: 8 thr/row, 8 floats each.  V tile: 32 rows, 8 d each.
    const int krow = tg >> 3,  kcol = (tg & 7) * 8;
    const int vrow = tg & 31,  vcol = (tg >> 5) * 8;
    const float* ksrc0 = Kp + bboff + (size_t)krow * D_ + kcol;
    const float* vsrc0 = Vp + bboff + (size_t)vrow * D_ + vcol;

    f32x4 kr[2], vr[2];
    auto load_tile = [&](int t) {              // t = global tile index
        const float* ks = ksrc0 + (size_t)t * KVBLK * D_;
        const float* vs = vsrc0 + (size_t)t * KVBLK * D_;
        kr[0] = *reinterpret_cast<const f32x4*>(ks);
        kr[1] = *reinterpret_cast<const f32x4*>(ks + 4);
        vr[0] = *reinterpret_cast<const f32x4*>(vs);
        vr[1] = *reinterpret_cast<const f32x4*>(vs + 4);
    };

    auto write_tile = [&](int b) {
        char* kb = gbase + b * 8192;
        char* vb = kb + 4096;
        // K: row-major [32][64] bf16 (128B rows), XOR-swizzled (row&7)<<4
        bf16x8 w0;
#pragma unroll
        for (int j = 0; j < 4; ++j) { w0[j] = (__bf16)kr[0][j]; w0[4 + j] = (__bf16)kr[1][j]; }
        *reinterpret_cast<bf16x8*>(kb + krow * 128 + ((kcol * 2) ^ ((krow & 7) << 4))) = w0;
        // Vt: [64 d][32 kv] bf16 (64B rows), XOR-swizzled (d&7)<<3
#pragma unroll 8
        for (int i = 0; i < 8; ++i) {
            const int d = vcol + i;
            *reinterpret_cast<__bf16*>(vb + d * 64 + ((vrow * 2) ^ ((d & 7) << 3))) =
                (__bf16)vr[i >> 2][i & 3];
        }
    };

    // ---------------- accumulators / softmax state --------------------------
    f32x16 o0, o1;
#pragma unroll
    for (int i = 0; i < 16; ++i) { o0[i] = 0.f; o1[i] = 0.f; }
    float m_run = -1e30f, l_run = 0.f;

    const int kx = (qcol & 7) << 4;            // K-read swizzle for this lane's row

    load_tile(g);
    write_tile(0);
    __syncthreads();

    for (int it = 0; it < TPG; ++it) {
        const int cur = it & 1;
        if (it + 1 < TPG) load_tile(NG * (it + 1) + g);   // issue next loads early

        const char* kb = gbase + cur * 8192;
        const char* vb = kb + 4096;

        // ---- QK^T : S^T[kv][q] = mfma(A=K, B=Q^T), kv = 0..31 ----
        f32x16 s;
#pragma unroll
        for (int i = 0; i < 16; ++i) s[i] = 0.f;
        __builtin_amdgcn_s_setprio(1);
#pragma unroll
        for (int m = 0; m < 4; ++m) {
            const int col = m * 32 + h * 16;
            bf16x8 k0 = *reinterpret_cast<const bf16x8*>(kb + qcol * 128 + (col ^ kx));
            s = __builtin_amdgcn_mfma_f32_32x32x16_bf16(k0, qf[m], s, 0, 0, 0);
        }
        __builtin_amdgcn_s_setprio(0);

        // ---- online softmax (tree max, depth ~5) ----
        float t8[8];
#pragma unroll
        for (int i = 0; i < 8; ++i) t8[i] = fmaxf(s[i], s[8 + i]);
        float t4a = fmaxf(t8[0], t8[1]), t4b = fmaxf(t8[2], t8[3]);
        float t4c = fmaxf(t8[4], t8[5]), t4d = fmaxf(t8[6], t8[7]);
        float tmax = fmaxf(fmaxf(t4a, t4b), fmaxf(t4c, t4d));
        tmax = fmaxf(tmax, __shfl_xor(tmax, 32));

        if (!__all(tmax <= m_run + 16.0f)) {   // defer-max: p <= 2^(16*SL2E) ~ 7.4
            const float mnew  = fmaxf(m_run, tmax);
            const float alpha = fast_exp2((m_run - mnew) * SL2E);
            l_run *= alpha;
#pragma unroll
            for (int i = 0; i < 16; ++i) { o0[i] *= alpha; o1[i] *= alpha; }
            m_run = mnew;
        }

        const float nmk = -m_run * SL2E;
        float ps0 = 0.f, ps1 = 0.f, ps2 = 0.f, ps3 = 0.f;
        bf16x8 pfa, pfb;
#pragma unroll
        for (int i = 0; i < 4; ++i) {
            float p0 = fast_exp2(fmaf(s[i],      SL2E, nmk));
            float p1 = fast_exp2(fmaf(s[4 + i],  SL2E, nmk));
            float p2 = fast_exp2(fmaf(s[8 + i],  SL2E, nmk));
            float p3 = fast_exp2(fmaf(s[12 + i], SL2E, nmk));
            ps0 += p0; ps1 += p1; ps2 += p2; ps3 += p3;
            pfa[i] = (__bf16)p0; pfa[4 + i] = (__bf16)p1;
            pfb[i] = (__bf16)p2; pfb[4 + i] = (__bf16)p3;
        }
        l_run += (ps0 + ps1) + (ps2 + ps3);

        // ---- PV : O^T[d][q] += mfma(A=Vt, B=P) ----
        __builtin_amdgcn_s_setprio(1);
#pragma unroll
        for (int db = 0; db < 2; ++db) {
            const int drow = db * 32 + qcol;
            const char* vrowp = vb + drow * 64;
            const int vxx = (drow & 7) << 3;
            f32x16& oo = db ? o1 : o0;
#pragma unroll
            for (int sub = 0; sub < 2; ++sub) {
                const int cb = sub * 32 + h * 8;
                bf16x4 v0 = *reinterpret_cast<const bf16x4*>(vrowp + ((cb)      ^ vxx));
                bf16x4 v1 = *reinterpret_cast<const bf16x4*>(vrowp + ((cb + 16) ^ vxx));
                bf16x8 vf;
#pragma unroll
                for (int j = 0; j < 4; ++j) { vf[j] = v0[j]; vf[4 + j] = v1[j]; }
                oo = __builtin_amdgcn_mfma_f32_32x32x16_bf16(vf, sub ? pfb : pfa, oo, 0, 0, 0);
            }
        }
        __builtin_amdgcn_s_setprio(0);

        if (it + 1 < TPG) write_tile(cur ^ 1);
        __syncthreads();
    }

    // ---------------- 4-way cross-group combine through LDS -----------------
    // (m,l) exchange, then pairwise O merges reusing the 64 KiB staging space.
    const float lt = l_run + __shfl_xor(l_run, 32);   // group-total l
    float* mlF  = (float*)smem;                        // 4 KiB  [g][q]{m,l}
    float* slab = (float*)smem;                        // slabA = slab, slabB = slab+8192
    const int q  = w * 32 + qcol;

    if (h == 0) {
        mlF[(g * QBLK + q) * 2]     = m_run;
        mlF[(g * QBLK + q) * 2 + 1] = lt;
    }
    __syncthreads();

    float mg[4], lg[4];
#pragma unroll
    for (int gg = 0; gg < 4; ++gg) {
        mg[gg] = mlF[(gg * QBLK + q) * 2];
        lg[gg] = mlF[(gg * QBLK + q) * 2 + 1];
    }
    const float mm = fmaxf(fmaxf(mg[0], mg[1]), fmaxf(mg[2], mg[3]));
    float L = 0.f;
#pragma unroll
    for (int gg = 0; gg < 4; ++gg) L += fast_exp2((mg[gg] - mm) * SL2E) * lg[gg];
    const float a_self = fast_exp2((m_run - mm) * SL2E);
    const float inv = 1.0f / L;
    __syncthreads();                            // ml reads done before slab overwrite

    // slab layout [64 d][128 q] f32; slabA for pair(0,1), slabB for pair(2,3)
    const int dl0 = 4 * h;                      // d_local base for reg r: (r&3)+8*(r>>2)+4h
    auto slab_write = [&](float* sb, const f32x16& oo, int db, float scale) {
#pragma unroll
        for (int r = 0; r < 16; ++r) {
            const int d = db * 32 + (r & 3) + 8 * (r >> 2) + dl0;
            sb[d * 128 + q] = scale * oo[r];
        }
    };
    auto slab_add = [&](const float* sb, f32x16& oo, int db, float scale) {
#pragma unroll
        for (int r = 0; r < 16; ++r) {
            const int d = db * 32 + (r & 3) + 8 * (r >> 2) + dl0;
            oo[r] = fmaf(scale, oo[r], sb[d * 128 + q]);
        }
    };

    if (g == 1) { slab_write(slab, o0, 0, a_self);        slab_write(slab, o1, 1, a_self); }
    if (g == 3) { slab_write(slab + 8192, o0, 0, a_self); slab_write(slab + 8192, o1, 1, a_self); }
    __syncthreads();

    if (g == 0) { slab_add(slab, o0, 0, a_self);        slab_add(slab, o1, 1, a_self); }
    if (g == 2) { slab_add(slab + 8192, o0, 0, a_self); slab_add(slab + 8192, o1, 1, a_self); }
    __syncthreads();

    if (g == 2) { slab_write(slab, o0, 0, 1.0f); slab_write(slab, o1, 1, 1.0f); }
    __syncthreads();

    if (g == 0) {
#pragma unroll
        for (int r = 0; r < 16; ++r) {
            const int d0 = (r & 3) + 8 * (r >> 2) + dl0;
            o0[r] = (o0[r] + slab[d0 * 128 + q]) * inv;
            o1[r] = (o1[r] + slab[(32 + d0) * 128 + q]) * inv;
        }
        float* orow = Op + bboff + (size_t)(q0w + qcol) * D_;
#pragma unroll
        for (int gg8 = 0; gg8 < 4; ++gg8) {
            f32x4 v, v2;
#pragma unroll
            for (int r = 0; r < 4; ++r) { v[r] = o0[4 * gg8 + r]; v2[r] = o1[4 * gg8 + r]; }
            *reinterpret_cast<f32x4*>(orow + gg8 * 8 + 4 * h)      = v;
            *reinterpret_cast<f32x4*>(orow + 32 + gg8 * 8 + 4 * h) = v2;
        }
    }
}

extern "C" void kernel_launch(void* const* d_in, const int* in_sizes, int n_in,
                              void* d_out, int out_size, void* d_ws, size_t ws_size,
                              hipStream_t stream) {
    const float* Q = (const float*)d_in[0];
    const float* K = (const float*)d_in[1];
    const float* V = (const float*)d_in[2];
    float* O = (float*)d_out;
    dim3 grid(256), block(1024);
    hipLaunchKernelGGL(attn_fwd, grid, block, 0, stream, Q, K, V, O);
}

// Round 5
// 39.626 us; speedup vs baseline: 2.1625x; 1.0500x over previous
//
#include <hip/hip_runtime.h>

typedef __attribute__((ext_vector_type(8)))  __bf16 bf16x8;
typedef __attribute__((ext_vector_type(4)))  __bf16 bf16x4;
typedef __attribute__((ext_vector_type(16))) float  f32x16;
typedef __attribute__((ext_vector_type(4)))  float  f32x4;

#define B_    16
#define N_    2048
#define D_    64
#define QBLK  128            // q rows per block (4 q-waves x 32, shared by all groups)
#define KVBLK 32
#define NT    (N_ / KVBLK)   // 64 tiles
#define NG    4              // KV groups per block (16 waves total)
#define TPG   (NT / NG)      // 16 tiles per group

// LDS geometry: per group, 2 slots of (K 4096 B + Vt 64 rows x 72 B = 4608 B)
#define VSTR    72
#define SLOT_SZ 8704
#define GRP_SZ  (2 * SLOT_SZ)        // 17408
#define SMEM_SZ (4 * GRP_SZ)         // 69632

static __device__ __forceinline__ float fast_exp2(float x) {
#if __has_builtin(__builtin_amdgcn_exp2f)
    return __builtin_amdgcn_exp2f(x);
#else
    return __expf(x * 0.6931471805599453f);
#endif
}

__global__ __attribute__((amdgpu_waves_per_eu(4, 4))) __launch_bounds__(1024)
void attn_fwd(const float* __restrict__ Qp, const float* __restrict__ Kp,
              const float* __restrict__ Vp, float* __restrict__ Op)
{
    __shared__ __align__(16) char smem[SMEM_SZ];

    const int tid  = threadIdx.x;
    const int g    = tid >> 8;                 // KV group 0..3
    const int tg   = tid & 255;                // thread within group
    const int lane = tid & 63;
    const int w    = (tid >> 6) & 3;           // q-wave 0..3 within group
    const int h    = lane >> 5;
    const int qcol = lane & 31;

    const int bx    = blockIdx.x;              // grid 256 = 1 block/CU
    const int batch = ((bx & 7) << 1) | ((bx >> 3) & 1);   // 2 batches per XCD
    const int qtile = bx >> 4;                 // 0..15
    const int q0w   = qtile * QBLK + w * 32;

    const float SL2E = 0.18033688011112042f;   // (1/sqrt(64)) * log2(e)
    const size_t bboff = (size_t)batch * (N_ * D_);

    char* gbase = smem + g * GRP_SZ;

    // ---------------- Q fragments (registers, reused across all tiles) ------
    const float* qrow = Qp + bboff + (size_t)(q0w + qcol) * D_ + h * 8;
    bf16x8 qf[4];
#pragma unroll
    for (int m = 0; m < 4; ++m) {
        f32x4 a = *reinterpret_cast<const f32x4*>(qrow + m * 16);
        f32x4 b = *reinterpret_cast<const f32x4*>(qrow + m * 16 + 4);
#pragma unroll
        for (int j = 0; j < 4; ++j) { qf[m][j] = (__bf16)a[j]; qf[m][4 + j] = (__bf16)b[j]; }
    }

    // ---------------- staging (global -> reg -> LDS), 256 thr per group -----
    // K tile 32x64 fp32: 8 thr/row, 8 floats each.  V tile: 32 rows, 8 d each.
    const int krow = tg >> 3,  kcol = (tg & 7) * 8;
    const int vrow = tg & 31,  vcol = (tg >> 5) * 8;
    const float* ksrc0 = Kp + bboff + (size_t)krow * D_ + kcol;
    const float* vsrc0 = Vp + bboff + (size_t)vrow * D_ + vcol;

    f32x4 kr[2], vr[2];
    auto load_tile = [&](int t) {              // t = global tile index
        const float* ks = ksrc0 + (size_t)t * KVBLK * D_;
        const float* vs = vsrc0 + (size_t)t * KVBLK * D_;
        kr[0] = *reinterpret_cast<const f32x4*>(ks);
        kr[1] = *reinterpret_cast<const f32x4*>(ks + 4);
        vr[0] = *reinterpret_cast<const f32x4*>(vs);
        vr[1] = *reinterpret_cast<const f32x4*>(vs + 4);
    };

    auto write_tile = [&](int b) {
        char* kb = gbase + b * SLOT_SZ;
        char* vb = kb + 4096;
        // K: row-major [32][64] bf16 (128B rows), XOR-swizzled (row&7)<<4
        bf16x8 w0;
#pragma unroll
        for (int j = 0; j < 4; ++j) { w0[j] = (__bf16)kr[0][j]; w0[4 + j] = (__bf16)kr[1][j]; }
        *reinterpret_cast<bf16x8*>(kb + krow * 128 + ((kcol * 2) ^ ((krow & 7) << 4))) = w0;
        // Vt: [64 d][32 kv] bf16, row stride 72 B (bank-walk, no XOR needed)
#pragma unroll 8
        for (int i = 0; i < 8; ++i) {
            const int d = vcol + i;
            *reinterpret_cast<__bf16*>(vb + d * VSTR + vrow * 2) =
                (__bf16)vr[i >> 2][i & 3];
        }
    };

    // ---------------- accumulators / softmax state --------------------------
    f32x16 o0, o1;
#pragma unroll
    for (int i = 0; i < 16; ++i) { o0[i] = 0.f; o1[i] = 0.f; }
    float m_run = -1e30f, l_run = 0.f;

    const int kx = (qcol & 7) << 4;            // K-read swizzle for this lane's row

    load_tile(g);
    write_tile(0);
    __syncthreads();

    for (int it = 0; it < TPG; ++it) {
        const int cur = it & 1;
        if (it + 1 < TPG) load_tile(NG * (it + 1) + g);   // issue next loads early

        const char* kb = gbase + cur * SLOT_SZ;
        const char* vb = kb + 4096;

        // ---- QK^T : S^T[kv][q] = mfma(A=K, B=Q^T), kv = 0..31 ----
        f32x16 s;
#pragma unroll
        for (int i = 0; i < 16; ++i) s[i] = 0.f;
        __builtin_amdgcn_s_setprio(1);
#pragma unroll
        for (int m = 0; m < 4; ++m) {
            const int col = m * 32 + h * 16;
            bf16x8 k0 = *reinterpret_cast<const bf16x8*>(kb + qcol * 128 + (col ^ kx));
            s = __builtin_amdgcn_mfma_f32_32x32x16_bf16(k0, qf[m], s, 0, 0, 0);
        }
        __builtin_amdgcn_s_setprio(0);

        // ---- online softmax (tree max) ----
        float t8[8];
#pragma unroll
        for (int i = 0; i < 8; ++i) t8[i] = fmaxf(s[i], s[8 + i]);
        float t4a = fmaxf(t8[0], t8[1]), t4b = fmaxf(t8[2], t8[3]);
        float t4c = fmaxf(t8[4], t8[5]), t4d = fmaxf(t8[6], t8[7]);
        float tmax = fmaxf(fmaxf(t4a, t4b), fmaxf(t4c, t4d));
        tmax = fmaxf(tmax, __shfl_xor(tmax, 32));

        if (!__all(tmax <= m_run + 16.0f)) {   // defer-max: p <= 2^(16*SL2E) ~ 7.4
            const float mnew  = fmaxf(m_run, tmax);
            const float alpha = fast_exp2((m_run - mnew) * SL2E);
            l_run *= alpha;
#pragma unroll
            for (int i = 0; i < 16; ++i) { o0[i] *= alpha; o1[i] *= alpha; }
            m_run = mnew;
        }

        const float nmk = -m_run * SL2E;
        float ps0 = 0.f, ps1 = 0.f, ps2 = 0.f, ps3 = 0.f;
        bf16x8 pfa, pfb;
#pragma unroll
        for (int i = 0; i < 4; ++i) {
            float p0 = fast_exp2(fmaf(s[i],      SL2E, nmk));
            float p1 = fast_exp2(fmaf(s[4 + i],  SL2E, nmk));
            float p2 = fast_exp2(fmaf(s[8 + i],  SL2E, nmk));
            float p3 = fast_exp2(fmaf(s[12 + i], SL2E, nmk));
            ps0 += p0; ps1 += p1; ps2 += p2; ps3 += p3;
            pfa[i] = (__bf16)p0; pfa[4 + i] = (__bf16)p1;
            pfb[i] = (__bf16)p2; pfb[4 + i] = (__bf16)p3;
        }
        l_run += (ps0 + ps1) + (ps2 + ps3);

        // ---- PV : O^T[d][q] += mfma(A=Vt, B=P) ----
        __builtin_amdgcn_s_setprio(1);
#pragma unroll
        for (int db = 0; db < 2; ++db) {
            const int drow = db * 32 + qcol;
            const char* vrowp = vb + drow * VSTR;
            f32x16& oo = db ? o1 : o0;
#pragma unroll
            for (int sub = 0; sub < 2; ++sub) {
                const int cb = sub * 32 + h * 8;
                bf16x4 v0 = *reinterpret_cast<const bf16x4*>(vrowp + cb);
                bf16x4 v1 = *reinterpret_cast<const bf16x4*>(vrowp + cb + 16);
                bf16x8 vf;
#pragma unroll
                for (int j = 0; j < 4; ++j) { vf[j] = v0[j]; vf[4 + j] = v1[j]; }
                oo = __builtin_amdgcn_mfma_f32_32x32x16_bf16(vf, sub ? pfb : pfa, oo, 0, 0, 0);
            }
        }
        __builtin_amdgcn_s_setprio(0);

        if (it + 1 < TPG) write_tile(cur ^ 1);
        __syncthreads();
    }

    // ---------------- 4-way cross-group combine through LDS -----------------
    const float lt = l_run + __shfl_xor(l_run, 32);   // group-total l
    float* mlF  = (float*)smem;                        // 4 KiB  [g][q]{m,l}
    float* slab = (float*)smem;                        // slabA = slab, slabB = slab+8192 floats
    const int q  = w * 32 + qcol;

    if (h == 0) {
        mlF[(g * QBLK + q) * 2]     = m_run;
        mlF[(g * QBLK + q) * 2 + 1] = lt;
    }
    __syncthreads();

    float mg[4], lg[4];
#pragma unroll
    for (int gg = 0; gg < 4; ++gg) {
        mg[gg] = mlF[(gg * QBLK + q) * 2];
        lg[gg] = mlF[(gg * QBLK + q) * 2 + 1];
    }
    const float mm = fmaxf(fmaxf(mg[0], mg[1]), fmaxf(mg[2], mg[3]));
    float L = 0.f;
#pragma unroll
    for (int gg = 0; gg < 4; ++gg) L += fast_exp2((mg[gg] - mm) * SL2E) * lg[gg];
    const float a_self = fast_exp2((m_run - mm) * SL2E);
    const float inv = 1.0f / L;
    __syncthreads();                            // ml reads done before slab overwrite

    // slab layout [64 d][128 q] f32; slabA for pair(0,1), slabB for pair(2,3)
    const int dl0 = 4 * h;                      // d_local base for reg r: (r&3)+8*(r>>2)+4h
    auto slab_write = [&](float* sb, const f32x16& oo, int db, float scale) {
#pragma unroll
        for (int r = 0; r < 16; ++r) {
            const int d = db * 32 + (r & 3) + 8 * (r >> 2) + dl0;
            sb[d * 128 + q] = scale * oo[r];
        }
    };
    auto slab_add = [&](const float* sb, f32x16& oo, int db, float scale) {
#pragma unroll
        for (int r = 0; r < 16; ++r) {
            const int d = db * 32 + (r & 3) + 8 * (r >> 2) + dl0;
            oo[r] = fmaf(scale, oo[r], sb[d * 128 + q]);
        }
    };

    if (g == 1) { slab_write(slab, o0, 0, a_self);        slab_write(slab, o1, 1, a_self); }
    if (g == 3) { slab_write(slab + 8192, o0, 0, a_self); slab_write(slab + 8192, o1, 1, a_self); }
    __syncthreads();

    if (g == 0) { slab_add(slab, o0, 0, a_self);        slab_add(slab, o1, 1, a_self); }
    if (g == 2) { slab_add(slab + 8192, o0, 0, a_self); slab_add(slab + 8192, o1, 1, a_self); }
    __syncthreads();

    if (g == 2) { slab_write(slab, o0, 0, 1.0f); slab_write(slab, o1, 1, 1.0f); }
    __syncthreads();

    if (g == 0) {
#pragma unroll
        for (int r = 0; r < 16; ++r) {
            const int d0 = (r & 3) + 8 * (r >> 2) + dl0;
            o0[r] = (o0[r] + slab[d0 * 128 + q]) * inv;
            o1[r] = (o1[r] + slab[(32 + d0) * 128 + q]) * inv;
        }
        float* orow = Op + bboff + (size_t)(q0w + qcol) * D_;
#pragma unroll
        for (int gg8 = 0; gg8 < 4; ++gg8) {
            f32x4 v, v2;
#pragma unroll
            for (int r = 0; r < 4; ++r) { v[r] = o0[4 * gg8 + r]; v2[r] = o1[4 * gg8 + r]; }
            *reinterpret_cast<f32x4*>(orow + gg8 * 8 + 4 * h)      = v;
            *reinterpret_cast<f32x4*>(orow + 32 + gg8 * 8 + 4 * h) = v2;
        }
    }
}

extern "C" void kernel_launch(void* const* d_in, const int* in_sizes, int n_in,
                              void* d_out, int out_size, void* d_ws, size_t ws_size,
                              hipStream_t stream) {
    const float* Q = (const float*)d_in[0];
    const float* K = (const float*)d_in[1];
    const float* V = (const float*)d_in[2];
    float* O = (float*)d_out;
    dim3 grid(256), block(1024);
    hipLaunchKernelGGL(attn_fwd, grid, block, 0, stream, Q, K, V, O);
}